// Round 9
// baseline (419.231 us; speedup 1.0000x reference)
//
#include <hip/hip_runtime.h>
#include <hip/hip_bf16.h>

static constexpr int HN = 32;     // Hemb == Hgcn == 32
static constexpr int NIN = 128;
static constexpr int CH1 = 8192;  // edges per phase-1/bhist block

__device__ __forceinline__ float bf2f(unsigned short u) {
    union { unsigned int i; float f; } v;
    v.i = ((unsigned int)u) << 16;
    return v.f;
}
__device__ __forceinline__ float ldf(const void* p, size_t i, int isbf) {
    return isbf ? bf2f(((const unsigned short*)p)[i]) : ((const float*)p)[i];
}

// K0: bf16-vs-fp32 input sniff (validated fp32; kept as insurance).
__global__ void detect_kernel(const unsigned int* __restrict__ xw,
                              int* __restrict__ flag)
{
    int lane = threadIdx.x;          // 64 threads
    int hits = 0;
    #pragma unroll
    for (int k = 0; k < 2; ++k) {
        unsigned int w = xw[lane + 64 * k];
        float a = bf2f((unsigned short)(w & 0xFFFFu));
        float aa = fabsf(a);
        if (a == 0.0f || (aa >= 0.000244140625f && aa <= 32.0f)) hits++;
    }
    #pragma unroll
    for (int m = 32; m; m >>= 1) hits += __shfl_xor(hits, m, 64);
    if (lane == 0) flag[0] = (hits >= 64) ? 1 : 0;
}

// K1: h = relu(x @ Wemb + bemb) -> fp32
__global__ __launch_bounds__(256) void embed1_kernel(
    const void* __restrict__ x,
    const void* __restrict__ Wemb,
    const void* __restrict__ bemb,
    const int* __restrict__ flagp,
    float* __restrict__ h, int N)
{
    __shared__ float We[NIN * HN];
    __shared__ float be[HN];
    __shared__ float xs[32][NIN];
    const int tid = threadIdx.x;
    const int isbf = flagp[0];

    for (int i = tid; i < NIN * HN; i += 256) We[i] = ldf(Wemb, i, isbf);
    if (tid < HN) be[tid] = ldf(bemb, tid, isbf);

    const int n0 = blockIdx.x * 32;
    if (isbf) {
        const ushort4* x4 = (const ushort4*)((const unsigned short*)x + (size_t)n0 * NIN);
        for (int i = tid; i < 32 * (NIN / 4); i += 256) {
            ushort4 u = x4[i];
            int base = i * 4, n = base >> 7, k = base & (NIN - 1);
            xs[n][k] = bf2f(u.x); xs[n][k + 1] = bf2f(u.y);
            xs[n][k + 2] = bf2f(u.z); xs[n][k + 3] = bf2f(u.w);
        }
    } else {
        const float4* x4 = (const float4*)((const float*)x + (size_t)n0 * NIN);
        for (int i = tid; i < 32 * (NIN / 4); i += 256) {
            float4 u = x4[i];
            int base = i * 4, n = base >> 7, k = base & (NIN - 1);
            xs[n][k] = u.x; xs[n][k + 1] = u.y;
            xs[n][k + 2] = u.z; xs[n][k + 3] = u.w;
        }
    }
    __syncthreads();

    const int f = tid & 31, ns = tid >> 5;
    float a0 = be[f], a1 = be[f], a2 = be[f], a3 = be[f];
    #pragma unroll 8
    for (int k = 0; k < NIN; ++k) {
        float w = We[k * HN + f];
        a0 += xs[ns +  0][k] * w;
        a1 += xs[ns +  8][k] * w;
        a2 += xs[ns + 16][k] * w;
        a3 += xs[ns + 24][k] * w;
    }
    if (n0 + ns      < N) h[(size_t)(n0 + ns     ) * HN + f] = fmaxf(a0, 0.f);
    if (n0 + ns +  8 < N) h[(size_t)(n0 + ns +  8) * HN + f] = fmaxf(a1, 0.f);
    if (n0 + ns + 16 < N) h[(size_t)(n0 + ns + 16) * HN + f] = fmaxf(a2, 0.f);
    if (n0 + ns + 24 < N) h[(size_t)(n0 + ns + 24) * HN + f] = fmaxf(a3, 0.f);
}

// K2: coarse bucket histogram (bucket = col>>8), LDS-aggregated.
__global__ __launch_bounds__(512) void bhist_kernel(
    const int* __restrict__ col, int* __restrict__ bucket_cnt, int E, int B)
{
    __shared__ int hist[512];
    const int t = threadIdx.x;
    const int e0 = blockIdx.x * CH1;
    for (int i = t; i < B; i += 512) hist[i] = 0;
    __syncthreads();
    #pragma unroll
    for (int k = 0; k < CH1 / 512; ++k) {
        int e = e0 + k * 512 + t;
        if (e < E) atomicAdd(&hist[col[e] >> 8], 1);
    }
    __syncthreads();
    for (int i = t; i < B; i += 512)
        if (hist[i]) atomicAdd(&bucket_cnt[i], hist[i]);
}

// K3: exclusive scan of bucket counts (B <= 512); init cursors.
__global__ __launch_bounds__(512) void bscan_kernel(
    const int* __restrict__ bucket_cnt, int* __restrict__ bucket_base,
    int* __restrict__ bucket_cursor, int B, int E)
{
    __shared__ int sc[512];
    __shared__ int orig[512];
    const int t = threadIdx.x;
    int v0 = (t < B) ? bucket_cnt[t] : 0;
    sc[t] = v0; orig[t] = v0;
    __syncthreads();
    for (int o = 1; o < 512; o <<= 1) {
        int v = (t >= o) ? sc[t - o] : 0;
        __syncthreads();
        sc[t] += v;
        __syncthreads();
    }
    if (t < B) {
        int ex = sc[t] - orig[t];
        bucket_base[t] = ex;
        bucket_cursor[t] = ex;
    }
    if (t == 0) bucket_base[B] = E;
}

// K4 (phase1): bucketize edges -> packed words (row<<8 | col&255).
// Direct writes: per-bucket runs are contiguous, L2 absorbs partial lines.
__global__ __launch_bounds__(512) void phase1_kernel(
    const int* __restrict__ row, const int* __restrict__ col,
    int* __restrict__ bucket_cursor, int* __restrict__ bucketed, int E, int B)
{
    __shared__ int hist[512];
    __shared__ int gbase[512];
    const int t = threadIdx.x;
    const int e0 = blockIdx.x * CH1;

    for (int i = t; i < B; i += 512) hist[i] = 0;
    __syncthreads();
    #pragma unroll
    for (int k = 0; k < CH1 / 512; ++k) {
        int e = e0 + k * 512 + t;
        if (e < E) atomicAdd(&hist[col[e] >> 8], 1);
    }
    __syncthreads();
    for (int i = t; i < B; i += 512) {
        int hc = hist[i];
        gbase[i] = hc ? atomicAdd(&bucket_cursor[i], hc) : 0;
        hist[i] = 0;                      // becomes rank counter
    }
    __syncthreads();
    #pragma unroll
    for (int k = 0; k < CH1 / 512; ++k) {
        int e = e0 + k * 512 + t;
        if (e < E) {
            int c = col[e], r = row[e];
            int b = c >> 8;
            int lr = atomicAdd(&hist[b], 1);
            bucketed[gbase[b] + lr] = (r << 8) | (c & 255);
        }
    }
}

// K5 (phase2): one block per bucket. Counts per-node in LDS, local scan
// gives rowptr (bucket_base[b] + scan), then places csr_src directly
// (contiguous ~32 KB segment -> L2-friendly). Replaces phase2a+scan1/2/3+2b.
__global__ __launch_bounds__(256) void phase2_kernel(
    const int* __restrict__ bucketed, const int* __restrict__ bucket_base,
    int* __restrict__ rowptr, int* __restrict__ csr_src, int N, int E)
{
    __shared__ int cnt[256];
    __shared__ int sc[256];
    __shared__ int base[256];
    const int t = threadIdx.x, b = blockIdx.x;
    const int s0 = bucket_base[b], s1 = bucket_base[b + 1];
    const int node0 = b << 8;
    cnt[t] = 0;
    __syncthreads();
    for (int i = s0 + t; i < s1; i += 256)
        atomicAdd(&cnt[bucketed[i] & 255], 1);
    __syncthreads();
    int myc = cnt[t];
    sc[t] = myc;
    __syncthreads();
    for (int o = 1; o < 256; o <<= 1) {
        int v = (t >= o) ? sc[t - o] : 0;
        __syncthreads();
        sc[t] += v;
        __syncthreads();
    }
    int ex = s0 + sc[t] - myc;            // exclusive prefix within bucket
    base[t] = ex;
    int node = node0 + t;
    if (node < N) rowptr[node] = ex;
    if (b == (int)gridDim.x - 1 && t == 0) rowptr[N] = E;
    cnt[t] = 0;
    __syncthreads();
    for (int i = s0 + t; i < s1; i += 256) {
        int w = bucketed[i];
        int lc = w & 255;
        int pos = base[lc] + atomicAdd(&cnt[lc], 1);
        csr_src[pos] = w >> 8;
    }
}

// K6: hws = dis * (h @ Wgcn)   (overwrites the bucketed region)
__global__ __launch_bounds__(256) void embed2_kernel(
    const float* __restrict__ h, const void* __restrict__ Wgcn,
    const int* __restrict__ rowptr, const int* __restrict__ flagp,
    float* __restrict__ hws, int N)
{
    __shared__ float Wg[HN * HN];
    __shared__ float hs[32][HN + 1];
    const int tid = threadIdx.x;
    const int isbf = flagp[0];
    for (int i = tid; i < HN * HN; i += 256) Wg[i] = ldf(Wgcn, i, isbf);
    const int n0 = blockIdx.x * 32;
    for (int i = tid; i < 32 * HN; i += 256) {
        int n = i >> 5, f = i & 31;
        hs[n][f] = (n0 + n < N) ? h[(size_t)(n0 + n) * HN + f] : 0.f;
    }
    __syncthreads();
    const int f = tid & 31, ns = tid >> 5;
    #pragma unroll
    for (int g = 0; g < 4; ++g) {
        int n = ns + 8 * g, v = n0 + n;
        if (v < N) {
            float acc = 0.f;
            #pragma unroll
            for (int k = 0; k < HN; ++k) acc += hs[n][k] * Wg[k * HN + f];
            float dis = rsqrtf((float)(rowptr[v + 1] - rowptr[v]) + 1.0f);
            hws[(size_t)v * HN + f] = dis * acc;
        }
    }
}

// K7 (passB): fused gather pass, online softmax, zero fp32 atomics.
// Software-pipelined csr_src index prefetch.
__global__ __launch_bounds__(256) void passB_kernel(
    const float* __restrict__ h, const float* __restrict__ hws,
    const int* __restrict__ csr_src, const int* __restrict__ rowptr,
    const void* __restrict__ t, const void* __restrict__ bgcn,
    const int* __restrict__ flagp,
    float* __restrict__ outr, float* __restrict__ outz,
    float* __restrict__ out0_ml, float* __restrict__ denout, int N)
{
    const int tid = threadIdx.x;
    const int lane = tid & 31;
    const int sub = lane >> 3;
    const int j = lane & 7;
    const int v = blockIdx.x * 8 + (tid >> 5);
    if (v >= N) return;
    const int isbf = flagp[0];

    const float4* h4 = (const float4*)h;
    const float4* w4 = (const float4*)hws;
    float4 hv = h4[(size_t)v * 8 + j];
    float4 wsv = w4[(size_t)v * 8 + j];
    const int s = rowptr[v], e2 = rowptr[v + 1];

    float m = -1e30f, den = 0.f, num = 0.f;
    float ax = 0.f, ay = 0.f, az = 0.f, aw = 0.f;
    int i = s + sub;
    int r = (i < e2) ? csr_src[i] : 0;
    while (i < e2) {
        int in = i + 4;
        int rn = (in < e2) ? csr_src[in] : 0;
        float4 hr = h4[(size_t)r * 8 + j];
        float4 wr = w4[(size_t)r * 8 + j];
        float tr = ldf(t, r, isbf);
        float p = hv.x * hr.x + hv.y * hr.y + hv.z * hr.z + hv.w * hr.w;
        p += __shfl_xor(p, 1, 32);
        p += __shfl_xor(p, 2, 32);
        p += __shfl_xor(p, 4, 32);
        float mn = fmaxf(m, p);
        float corr = __expf(m - mn);
        float a = __expf(p - mn);
        den = den * corr + a;
        num = num * corr + a * tr;
        m = mn;
        ax += wr.x; ay += wr.y; az += wr.z; aw += wr.w;
        i = in; r = rn;
    }
    #pragma unroll
    for (int o = 8; o <= 16; o <<= 1) {
        float mo = __shfl_xor(m, o, 32);
        float dno = __shfl_xor(den, o, 32);
        float nmo = __shfl_xor(num, o, 32);
        float mn = fmaxf(m, mo);
        float ca = __expf(m - mn), cb = __expf(mo - mn);
        den = den * ca + dno * cb;
        num = num * ca + nmo * cb;
        m = mn;
        ax += __shfl_xor(ax, o, 32);
        ay += __shfl_xor(ay, o, 32);
        az += __shfl_xor(az, o, 32);
        aw += __shfl_xor(aw, o, 32);
    }

    float dv = rsqrtf((float)(e2 - s) + 1.0f);
    float4 rep;
    rep.x = hv.x + fmaxf(dv * (ax + wsv.x) + ldf(bgcn, 4 * j + 0, isbf), 0.f);
    rep.y = hv.y + fmaxf(dv * (ay + wsv.y) + ldf(bgcn, 4 * j + 1, isbf), 0.f);
    rep.z = hv.z + fmaxf(dv * (az + wsv.z) + ldf(bgcn, 4 * j + 2, isbf), 0.f);
    rep.w = hv.w + fmaxf(dv * (aw + wsv.w) + ldf(bgcn, 4 * j + 3, isbf), 0.f);
    if (sub == 0)
        ((float4*)outr)[(size_t)v * 8 + j] = rep;
    if (lane == 0) {
        outz[v]    = num / fmaxf(den, 1e-37f);
        out0_ml[v] = m;
        denout[v]  = den;
    }
}

// K8a/K8b: global max over per-node local maxes
__global__ __launch_bounds__(256) void amax1_kernel(
    const float* __restrict__ ml, float* __restrict__ bmax2, int N)
{
    float m = -INFINITY;
    for (int i = blockIdx.x * 256 + threadIdx.x; i < N; i += 256 * 256)
        m = fmaxf(m, ml[i]);
    #pragma unroll
    for (int s = 32; s; s >>= 1) m = fmaxf(m, __shfl_xor(m, s, 64));
    __shared__ float sm[4];
    if ((threadIdx.x & 63) == 0) sm[threadIdx.x >> 6] = m;
    __syncthreads();
    if (threadIdx.x == 0)
        bmax2[blockIdx.x] = fmaxf(fmaxf(sm[0], sm[1]), fmaxf(sm[2], sm[3]));
}
__global__ __launch_bounds__(256) void amax2_kernel(
    const float* __restrict__ bmax2, float* __restrict__ amax)
{
    float m = bmax2[threadIdx.x];
    #pragma unroll
    for (int s = 32; s; s >>= 1) m = fmaxf(m, __shfl_xor(m, s, 64));
    __shared__ float sm[4];
    if ((threadIdx.x & 63) == 0) sm[threadIdx.x >> 6] = m;
    __syncthreads();
    if (threadIdx.x == 0) amax[0] = fmaxf(fmaxf(sm[0], sm[1]), fmaxf(sm[2], sm[3]));
}

// K9: exact epsilon correction + FF head.
__global__ __launch_bounds__(256) void final_kernel(
    const float* __restrict__ rep_in,
    const void* __restrict__ t, const int* __restrict__ flagp,
    const float* __restrict__ amax, const float* __restrict__ denarr,
    const void* __restrict__ W1, const void* __restrict__ b1,
    const void* __restrict__ W2, const void* __restrict__ b2,
    float* __restrict__ out0, float* __restrict__ outz, int N)
{
    __shared__ float W1s[34 * HN];
    __shared__ float b1s[HN], W2s[HN];
    __shared__ float b2s;
    const int tid = threadIdx.x;
    const int isbf = flagp[0];
    for (int i = tid; i < 34 * HN; i += 256) W1s[i] = ldf(W1, i, isbf);
    if (tid < HN) {
        b1s[tid] = ldf(b1, tid, isbf);
        W2s[tid] = ldf(W2, tid, isbf);
    }
    if (tid == 0) b2s = ldf(b2, 0, isbf);
    __syncthreads();

    const int lane = tid & 31;
    const int v = blockIdx.x * 8 + (tid >> 5);
    if (v >= N) return;

    float rep = rep_in[(size_t)v * HN + lane];
    float ml  = out0[v];
    float den = denarr[v];
    float zh  = outz[v];
    float am  = amax[0];
    float term = (1e-8f / den) * expf(am - ml);
    float z = zh / (1.0f + term);
    float tv = ldf(t, v, isbf);

    float acc = b1s[lane] + tv * W1s[32 * HN + lane] + z * W1s[33 * HN + lane];
    #pragma unroll
    for (int k = 0; k < HN; ++k)
        acc += __shfl(rep, k, 32) * W1s[k * HN + lane];
    float f1 = fmaxf(acc, 0.f);
    float o = f1 * W2s[lane];
    #pragma unroll
    for (int m = 16; m; m >>= 1) o += __shfl_xor(o, m, 32);

    if (lane == 0) {
        out0[v] = o + b2s;
        outz[v] = z;
    }
}

extern "C" void kernel_launch(void* const* d_in, const int* in_sizes, int n_in,
                              void* d_out, int out_size, void* d_ws, size_t ws_size,
                              hipStream_t stream)
{
    const int N = out_size / 34;   // out[N] + rep[N*32] + z[N]
    const int E = in_sizes[2];

    const void* x    = d_in[0];
    const void* t    = d_in[1];
    const int* row   = (const int*)d_in[2];
    const int* col   = (const int*)d_in[3];
    const void* Wemb = d_in[4];
    const void* bemb = d_in[5];
    const void* Wgcn = d_in[6];
    const void* bgcn = d_in[7];
    const void* W1   = d_in[8];
    const void* b1   = d_in[9];
    const void* W2   = d_in[10];
    const void* b2   = d_in[11];

    const int B   = (N + 255) >> 8;       // coarse buckets (<=512 for N<=131072)
    const int NB1 = (E + CH1 - 1) / CH1;  // phase1/bhist blocks

    // ws (~39.2 MB): h | hwreg(bucketed->hws) | csr_src | rowptr | den
    //                | bucket_cnt | bucket_base | bucket_cursor | bmax2 | amax | flag
    char* wsb = (char*)d_ws;
    size_t off = 0;
    float* h        = (float*)(wsb + off); off += (size_t)N * HN * 4;
    size_t hwbytes  = (size_t)N * HN * 4;
    if ((size_t)E * 4 > hwbytes) hwbytes = (size_t)E * 4;
    char*  hwreg    = wsb + off;           off += hwbytes;
    int*   csr_src  = (int*)(wsb + off);   off += (size_t)E * 4;
    int*   rowptr   = (int*)(wsb + off);   off += (size_t)(N + 1) * 4;
    float* den      = (float*)(wsb + off); off += (size_t)N * 4;
    int*   bucket_cnt    = (int*)(wsb + off); off += (size_t)B * 4;
    int*   bucket_base   = (int*)(wsb + off); off += (size_t)(B + 1) * 4;
    int*   bucket_cursor = (int*)(wsb + off); off += (size_t)B * 4;
    float* bmax2    = (float*)(wsb + off); off += 256 * 4;
    float* amax     = (float*)(wsb + off); off += 4;
    int*   flag     = (int*)(wsb + off);   off += 4;

    int*   bucketed = (int*)hwreg;         // until phase2 completes
    float* hws      = (float*)hwreg;       // after phase2 (embed2 overwrites)

    hipMemsetAsync(bucket_cnt, 0, (size_t)B * 4, stream);

    detect_kernel<<<1, 64, 0, stream>>>((const unsigned int*)x, flag);
    embed1_kernel<<<(N + 31) / 32, 256, 0, stream>>>(x, Wemb, bemb, flag, h, N);

    bhist_kernel<<<NB1, 512, 0, stream>>>(col, bucket_cnt, E, B);
    bscan_kernel<<<1, 512, 0, stream>>>(bucket_cnt, bucket_base,
                                        bucket_cursor, B, E);
    phase1_kernel<<<NB1, 512, 0, stream>>>(row, col, bucket_cursor,
                                           bucketed, E, B);
    phase2_kernel<<<B, 256, 0, stream>>>(bucketed, bucket_base, rowptr,
                                         csr_src, N, E);
    embed2_kernel<<<(N + 31) / 32, 256, 0, stream>>>(h, Wgcn, rowptr, flag,
                                                     hws, N);

    float* outp = (float*)d_out;
    float* out0 = outp;
    float* outr = outp + N;
    float* outz = outp + (size_t)N * 33;

    passB_kernel<<<(N + 7) / 8, 256, 0, stream>>>(
        h, hws, csr_src, rowptr, t, bgcn, flag, outr, outz, out0, den, N);
    amax1_kernel<<<256, 256, 0, stream>>>(out0, bmax2, N);
    amax2_kernel<<<1, 256, 0, stream>>>(bmax2, amax);
    final_kernel<<<(N + 7) / 8, 256, 0, stream>>>(
        outr, t, flag, amax, den, W1, b1, W2, b2, out0, outz, N);
}